// Round 16
// baseline (17.832 us; speedup 1.0000x reference)
//
#include <hip/hip_runtime.h>

// LogNorm moment-matching, v16: ONE kernel, lean fusion.
// v10 (fused, per-iter A rebuild) = 16.5; v11 (2 kernels, pure K-loop) = 15.34.
// v16 = fused AND pure K-loop: per wave, afr[12] built ONCE post-barrier from
// f32 mcorr LDS (wave-uniform broadcast reads) x hoisted w factors — same
// f32-mul chain + single f16 cvt as build_A (absmax should stay 0.0078125).
//
//   e = exp(Z_mu + sigma^2/2); x1' = e/4; x2' = e*sigma/4        (C x G)
//   var_num'[s,g] = sum_{d<=c} sc * (w_sc w_sd corr_cd) * (x2'_c x2'_d)
//   Ssum'[s,g]    = W @ x1'; var = vn'/ss'^2 (scales cancel);
//   mu = log(ss') + log4 - var/2 ; sigma = sqrt(var)
//
// Geometry = v14 (best single-dispatch-candidate): 625 blocks x 512 thr
// (8 waves), 32 genes/block, panel p = i*8 + w, i in [0,12).
// MFMA 16x16x32_f16, layout as verified v2-v15.

#define S_STATES 16
#define C_TYPES  64
#define G_GENES  20000
#define OUT_HALF (S_STATES * G_GENES)
#define PER_WAVE 12

typedef _Float16 f16x2 __attribute__((ext_vector_type(2)));
typedef _Float16 f16x8 __attribute__((ext_vector_type(8)));
typedef float    f32x4 __attribute__((ext_vector_type(4)));

union Frag8 { f16x2 p[4]; f16x8 v; uint4 u; _Float16 h[8]; };

__global__ __launch_bounds__(512, 4)
void lognorm_one(const float* __restrict__ Z_mu,
                 const float* __restrict__ Z_sigma,
                 const float* __restrict__ corr,
                 const float* __restrict__ w,
                 float* __restrict__ out)
{
    __shared__ float mcf[C_TYPES][C_TYPES];   // sc*corr, f32 (16 KB)
    __shared__ f16x2 x2pT[32][35];            // [gene][d-pair]
    __shared__ f16x2 x1pT[32][35];
    __shared__ f16x2 x2tp[C_TYPES][21];       // [c][(g,g+16)]; broadcast
    __shared__ float accs[8][S_STATES][33];
    __shared__ float ssum_s[S_STATES][33];

    const int gt    = blockIdx.x;        // 0..624, 32 genes (exact)
    const int tid   = threadIdx.x;       // 0..511
    const int w4    = tid >> 6;          // wave 0..7 = K-interleave slot
    const int lane  = tid & 63;
    const int gl    = lane & 15;
    const int q     = lane >> 4;
    const int gbase = gt * 32;

    // ---- hoisted w factors (global, L1-resident 4 KB) ----
    float wdv[2][8];                     // w[gl][dh*32 + q*8 + j]
#pragma unroll
    for (int dh = 0; dh < 2; ++dh) {
        const float4 a = *(const float4*)(w + gl*C_TYPES + dh*32 + q*8);
        const float4 b = *(const float4*)(w + gl*C_TYPES + dh*32 + q*8 + 4);
        wdv[dh][0]=a.x; wdv[dh][1]=a.y; wdv[dh][2]=a.z; wdv[dh][3]=a.w;
        wdv[dh][4]=b.x; wdv[dh][5]=b.y; wdv[dh][6]=b.z; wdv[dh][7]=b.w;
    }
    float wcv[PER_WAVE];                 // w[gl][c_i]
#pragma unroll
    for (int i = 0; i < PER_WAVE; ++i) {
        const int c = i*8 + w4 - ((i >= 8) ? 32 : 0);
        wcv[i] = w[gl*C_TYPES + c];
    }

    // ---- X-phase: thread -> rows 2dp,2dp+1 ; genes gq, gq+16 ----
    {
        const int dp = tid >> 4;         // 0..31
        const int gq = tid & 15;         // 0..15
        const float* zm = Z_mu    + (2*dp) * G_GENES + gbase + gq;
        const float* zs = Z_sigma + (2*dp) * G_GENES + gbase + gq;
        const float m00 = zm[0], m01 = zm[16];
        const float m10 = zm[G_GENES], m11 = zm[G_GENES + 16];
        const float s00 = zs[0], s01 = zs[16];
        const float s10 = zs[G_GENES], s11 = zs[G_GENES + 16];
        const float e00 = __expf(fmaf(0.5f*s00, s00, m00)) * 0.25f;
        const float e01 = __expf(fmaf(0.5f*s01, s01, m01)) * 0.25f;
        const float e10 = __expf(fmaf(0.5f*s10, s10, m10)) * 0.25f;
        const float e11 = __expf(fmaf(0.5f*s11, s11, m11)) * 0.25f;
        const float x200 = e00*s00, x201 = e01*s01;
        const float x210 = e10*s10, x211 = e11*s11;
        f16x2 a;
        a.x = (_Float16)x200; a.y = (_Float16)x210; x2pT[gq][dp]      = a;
        a.x = (_Float16)x201; a.y = (_Float16)x211; x2pT[gq + 16][dp] = a;
        a.x = (_Float16)e00;  a.y = (_Float16)e10;  x1pT[gq][dp]      = a;
        a.x = (_Float16)e01;  a.y = (_Float16)e11;  x1pT[gq + 16][dp] = a;
        a.x = (_Float16)x200; a.y = (_Float16)x201; x2tp[2*dp][gq]    = a;
        a.x = (_Float16)x210; a.y = (_Float16)x211; x2tp[2*dp+1][gq]  = a;
    }

    // ---- mcorr build: thread -> row c = tid>>3, cols (tid&7)*8.. ----
    {
        const int c  = tid >> 3;
        const int d0 = (tid & 7) * 8;
        const float4 c0 = *(const float4*)(corr + c*C_TYPES + d0);
        const float4 c1 = *(const float4*)(corr + c*C_TYPES + d0 + 4);
        const float cv[8] = {c0.x,c0.y,c0.z,c0.w, c1.x,c1.y,c1.z,c1.w};
#pragma unroll
        for (int jj = 0; jj < 8; ++jj) {
            const int d = d0 + jj;
            const float sc = (d < c) ? 2.0f : (d == c ? 1.0f : 0.0f);
            mcf[c][d] = sc * cv[jj];
        }
    }
    __syncthreads();

    // ---- afr build: ONCE per wave; mcf row reads are wave-uniform
    //      (c depends only on i,w4) -> pure broadcast, conflict-free.
    //      Rounding chain identical to build_A: f16(((sc*cv)*wc)*wd) ----
    Frag8 afr[PER_WAVE];
#pragma unroll
    for (int i = 0; i < PER_WAVE; ++i) {
        const int dh = (i >= 8) ? 1 : 0;
        const int c  = i*8 + w4 - dh*32;
        const float* mrow = &mcf[c][dh*32 + q*8];
#pragma unroll
        for (int j = 0; j < 8; ++j)
            afr[i].h[j] = (_Float16)((mrow[j] * wcv[i]) * wdv[dh][j]);
    }

    // ---- B sources: xh (16 reads, reused 6x), xct (12 broadcast) ----
    f16x2 xh[2][4][2];                   // [dh][jp][t]
#pragma unroll
    for (int dh = 0; dh < 2; ++dh)
#pragma unroll
        for (int t = 0; t < 2; ++t)
#pragma unroll
            for (int jp = 0; jp < 4; ++jp)
                xh[dh][jp][t] = x2pT[gl + 16*t][dh*16 + q*4 + jp];

    f16x2 xct[PER_WAVE];
#pragma unroll
    for (int i = 0; i < PER_WAVE; ++i) {
        const int c = i*8 + w4 - ((i >= 8) ? 32 : 0);
        xct[i] = x2tp[c][gl];
    }

    // ---- K-loop: 12 x {8 pk_mul, 2 MFMA}; pure reg/LDS, no VMEM ----
    f32x4 acc0a = {0.f,0.f,0.f,0.f}, acc0b = {0.f,0.f,0.f,0.f};
    f32x4 acc1a = {0.f,0.f,0.f,0.f}, acc1b = {0.f,0.f,0.f,0.f};
#pragma unroll
    for (int i = 0; i < PER_WAVE; ++i) {
        const int dh = (i >= 8) ? 1 : 0;
        Frag8 b0, b1;
#pragma unroll
        for (int jp = 0; jp < 4; ++jp) {
            f16x2 s0; s0.x = xct[i].x; s0.y = xct[i].x;
            f16x2 s1; s1.x = xct[i].y; s1.y = xct[i].y;
            b0.p[jp] = s0 * xh[dh][jp][0];
            b1.p[jp] = s1 * xh[dh][jp][1];
        }
        if (i & 1) {
            acc0b = __builtin_amdgcn_mfma_f32_16x16x32_f16(afr[i].v, b0.v, acc0b, 0, 0, 0);
            acc1b = __builtin_amdgcn_mfma_f32_16x16x32_f16(afr[i].v, b1.v, acc1b, 0, 0, 0);
        } else {
            acc0a = __builtin_amdgcn_mfma_f32_16x16x32_f16(afr[i].v, b0.v, acc0a, 0, 0, 0);
            acc1a = __builtin_amdgcn_mfma_f32_16x16x32_f16(afr[i].v, b1.v, acc1a, 0, 0, 0);
        }
    }
    const f32x4 acc0 = acc0a + acc0b;
    const f32x4 acc1 = acc1a + acc1b;
#pragma unroll
    for (int r = 0; r < 4; ++r) {
        accs[w4][q*4 + r][gl]      = acc0[r];
        accs[w4][q*4 + r][gl + 16] = acc1[r];
    }

    // ---- Ssum GEMM: waves 0,1 -> gene subtiles 0,1; W-frags from w ----
    if (w4 < 2) {
        Frag8 wf0, wf1;
#pragma unroll
        for (int j = 0; j < 8; ++j) {
            wf0.h[j] = (_Float16)w[gl*C_TYPES + q*8 + j];
            wf1.h[j] = (_Float16)w[gl*C_TYPES + 32 + q*8 + j];
        }
        Frag8 x1f[2];
#pragma unroll
        for (int kk = 0; kk < 2; ++kk)
#pragma unroll
            for (int jp = 0; jp < 4; ++jp)
                x1f[kk].p[jp] = x1pT[gl + 16*w4][kk*16 + q*4 + jp];
        f32x4 sa = {0.f,0.f,0.f,0.f};
        sa = __builtin_amdgcn_mfma_f32_16x16x32_f16(wf0.v, x1f[0].v, sa, 0, 0, 0);
        sa = __builtin_amdgcn_mfma_f32_16x16x32_f16(wf1.v, x1f[1].v, sa, 0, 0, 0);
#pragma unroll
        for (int r = 0; r < 4; ++r) ssum_s[q*4 + r][gl + 16*w4] = sa[r];
    }
    __syncthreads();

    // ---- epilogue: thread -> (s = tid>>5, gene gx = tid&31) ----
    const int s  = tid >> 5;
    const int gx = tid & 31;
    float vn = 0.f;
#pragma unroll
    for (int k = 0; k < 8; ++k) vn += accs[k][s][gx];
    const float ss   = ssum_s[s][gx];                 // = Ssum/4
    const float rvar = fmaxf(vn, 0.f) / (ss * ss);    // scale cancels
    out[s * G_GENES + gbase + gx] =
        __logf(ss) + 1.3862943611f - 0.5f * rvar;     // + log 4
    out[OUT_HALF + s * G_GENES + gbase + gx] = sqrtf(rvar);
}

extern "C" void kernel_launch(void* const* d_in, const int* in_sizes, int n_in,
                              void* d_out, int out_size, void* d_ws, size_t ws_size,
                              hipStream_t stream) {
    const float* Z_mu      = (const float*)d_in[0];
    const float* Z_sigma   = (const float*)d_in[1];
    const float* corr      = (const float*)d_in[2];
    const float* cell_prob = (const float*)d_in[3];
    float* out = (float*)d_out;

    const int gtiles = G_GENES / 32;               // 625, exact
    lognorm_one<<<dim3(gtiles), dim3(512), 0, stream>>>(
        Z_mu, Z_sigma, corr, cell_prob, out);
}

// Round 17
// 15.701 us; speedup vs baseline: 1.1357x; 1.1357x over previous
//
#include <hip/hip_runtime.h>

// LogNorm moment-matching, FINAL = v11 (best measured: 15.34 us).
// 11-variant elimination matrix (v2-v16) pinned the floor at ~15.3us with
// all pipes <10% busy (R12 counters) — launch/latency envelope, not a HW
// throughput roofline. Irreducible kernel work ~3-4us (10.2MB rd + 2.6MB wr
// ~2us; 2.6 GFLOP MFMA ~0.3us; 1.28M exp ~0.3us; issue ~1-2us).
//
//   e = exp(Z_mu + sigma^2/2); x1' = e/4; x2' = e*sigma/4        (C x G)
//   var_num'[s,g] = sum_{d<=c} sc * (w_sc w_sd corr_cd) * (x2'_c x2'_d)
//   Ssum'[s,g]    = W @ x1'; var = vn'/ss'^2 (scales cancel);
//   mu = log(ss') + log4 - var/2 ; sigma = sqrt(var)
//
// MFMA 16x16x32_f16, layout verified v2-v16:
//   A-frag: lane(q,gl) = A[m=gl][k=q*8+j]   (m = state)
//   B-frag: lane(q,gl) = B[k=q*8+j][n=gl]   (n = gene)
//   C/D:    lane(q,gl) reg r = D[row=q*4+r][col=gl]

#define S_STATES 16
#define C_TYPES  64
#define G_GENES  20000
#define OUT_HALF (S_STATES * G_GENES)
#define NPAIR    96
#define PER_WAVE 24

typedef _Float16 f16x2 __attribute__((ext_vector_type(2)));
typedef _Float16 f16x8 __attribute__((ext_vector_type(8)));
typedef float    f32x4 __attribute__((ext_vector_type(4)));

union Frag8 { f16x2 p[4]; f16x8 v; uint4 u; _Float16 h[8]; };

// ---- Kernel P: frag-ordered f16 A panels (1 KB each; 98 KB total) ----
__global__ __launch_bounds__(64)
void build_A(const float* __restrict__ corr, const float* __restrict__ w,
             unsigned short* __restrict__ cwA)
{
    const int p    = blockIdx.x;          // 0..97
    const int lane = threadIdx.x;
    const int gl   = lane & 15;           // state (A row)
    const int q    = lane >> 4;
    Frag8 v;
    if (p < NPAIR) {
        const int dh = (p >= 64);
        const int c  = dh ? p - 32 : p;
        const int d0 = dh * 32 + q * 8;
        const float wc = w[gl * C_TYPES + c];
        const float4 c0 = *(const float4*)(corr + c * C_TYPES + d0);
        const float4 c1 = *(const float4*)(corr + c * C_TYPES + d0 + 4);
        const float4 w0 = *(const float4*)(w + gl * C_TYPES + d0);
        const float4 w1 = *(const float4*)(w + gl * C_TYPES + d0 + 4);
        const float cv[8] = {c0.x,c0.y,c0.z,c0.w,c1.x,c1.y,c1.z,c1.w};
        const float wv[8] = {w0.x,w0.y,w0.z,w0.w,w1.x,w1.y,w1.z,w1.w};
#pragma unroll
        for (int j = 0; j < 8; ++j) {
            const int d = d0 + j;
            const float sc = (d < c) ? 2.0f : (d == c ? 1.0f : 0.0f);
            v.h[j] = (_Float16)(sc * cv[j] * wc * wv[j]);
        }
    } else {                               // W panels for the Ssum GEMM
        const int k0 = (p - NPAIR) * 32 + q * 8;
        const float4 w0 = *(const float4*)(w + gl * C_TYPES + k0);
        const float4 w1 = *(const float4*)(w + gl * C_TYPES + k0 + 4);
        const float wv[8] = {w0.x,w0.y,w0.z,w0.w,w1.x,w1.y,w1.z,w1.w};
#pragma unroll
        for (int j = 0; j < 8; ++j) v.h[j] = (_Float16)wv[j];
    }
    *(uint4*)(cwA + (p << 9) + lane * 8) = v.u;
}

// ---- Kernel M: main ----
__global__ __launch_bounds__(256, 4)
void lognorm_main(const float* __restrict__ Z_mu,
                  const float* __restrict__ Z_sigma,
                  const unsigned short* __restrict__ cwA,
                  float* __restrict__ out)
{
    __shared__ f16x2 x2pT[32][35];       // [gene][d-pair]
    __shared__ f16x2 x1pT[32][35];
    __shared__ f16x2 x2tp[C_TYPES][21];  // [c][(g,g+16) pair]; broadcast
    __shared__ float accs[4][S_STATES][33];
    __shared__ float ssum_s[S_STATES][33];

    const int gt    = blockIdx.x;        // 0..624, 32 genes (exact)
    const int tid   = threadIdx.x;
    const int w     = tid >> 6;          // wave id = K-interleave slot
    const int lane  = tid & 63;
    const int gl    = lane & 15;
    const int q     = lane >> 4;
    const int gbase = gt * 32;

    // ---- X-phase: thread -> (d-pair dp = tid>>3, 2 genes x 2 subtiles) ----
    {
        const int dp = tid >> 3;
        const int gq = tid & 7;
        const int ga = gq * 2;
        const float* zm0 = Z_mu    + (2*dp) * G_GENES + gbase + ga;
        const float* zs0 = Z_sigma + (2*dp) * G_GENES + gbase + ga;
        const float2 m00 = *(const float2*)zm0;
        const float2 m01 = *(const float2*)(zm0 + 16);
        const float2 m10 = *(const float2*)(zm0 + G_GENES);
        const float2 m11 = *(const float2*)(zm0 + G_GENES + 16);
        const float2 s00 = *(const float2*)zs0;
        const float2 s01 = *(const float2*)(zs0 + 16);
        const float2 s10 = *(const float2*)(zs0 + G_GENES);
        const float2 s11 = *(const float2*)(zs0 + G_GENES + 16);
        float x1v[2][2][2], x2v[2][2][2];   // [row r][half h][gene j]
#define XDO(r,h,j,M,S) { const float s_=(S); const float e_=__expf(fmaf(0.5f*s_,s_,(M)))*0.25f; \
                         x1v[r][h][j]=e_; x2v[r][h][j]=e_*s_; }
        XDO(0,0,0, m00.x, s00.x) XDO(0,0,1, m00.y, s00.y)
        XDO(0,1,0, m01.x, s01.x) XDO(0,1,1, m01.y, s01.y)
        XDO(1,0,0, m10.x, s10.x) XDO(1,0,1, m10.y, s10.y)
        XDO(1,1,0, m11.x, s11.x) XDO(1,1,1, m11.y, s11.y)
#undef XDO
#pragma unroll
        for (int h = 0; h < 2; ++h)
#pragma unroll
            for (int j = 0; j < 2; ++j) {
                const int g = ga + j + 16 * h;
                f16x2 a, b;
                a.x = (_Float16)x2v[0][h][j]; a.y = (_Float16)x2v[1][h][j];
                b.x = (_Float16)x1v[0][h][j]; b.y = (_Float16)x1v[1][h][j];
                x2pT[g][dp] = a;
                x1pT[g][dp] = b;
            }
#pragma unroll
        for (int r = 0; r < 2; ++r)
#pragma unroll
            for (int j = 0; j < 2; ++j) {
                f16x2 a;
                a.x = (_Float16)x2v[r][0][j];   // gene subtile 0
                a.y = (_Float16)x2v[r][1][j];   // gene subtile 1
                x2tp[2*dp + r][ga + j] = a;
            }
    }
    __syncthreads();

    // ---- B sources: xh (16 reads, reused 12x), xct (24 broadcast) ----
    f16x2 xh[2][4][2];                   // [dh][jp][t]
#pragma unroll
    for (int dh = 0; dh < 2; ++dh)
#pragma unroll
        for (int t = 0; t < 2; ++t)
#pragma unroll
            for (int jp = 0; jp < 4; ++jp)
                xh[dh][jp][t] = x2pT[gl + 16*t][dh*16 + q*4 + jp];

    f16x2 xct[PER_WAVE];
#pragma unroll
    for (int i = 0; i < PER_WAVE; ++i) {
        const int c = i*4 + w - ((i >= 16) ? 32 : 0);
        xct[i] = x2tp[c][gl];
    }

    // ---- K-loop: 24 x {A-load(b128), 8 pk_mul, 2 MFMA}; 4 acc chains ----
    const unsigned short* Abase = cwA + (w << 9) + lane * 8;
    f32x4 acc0a = {0.f,0.f,0.f,0.f}, acc0b = {0.f,0.f,0.f,0.f};
    f32x4 acc1a = {0.f,0.f,0.f,0.f}, acc1b = {0.f,0.f,0.f,0.f};
#pragma unroll
    for (int i = 0; i < PER_WAVE; ++i) {
        Frag8 af; af.u = *(const uint4*)(Abase + (i << 11));
        const int dh = (i >= 16) ? 1 : 0;
        Frag8 b0, b1;
#pragma unroll
        for (int jp = 0; jp < 4; ++jp) {
            f16x2 s0; s0.x = xct[i].x; s0.y = xct[i].x;
            f16x2 s1; s1.x = xct[i].y; s1.y = xct[i].y;
            b0.p[jp] = s0 * xh[dh][jp][0];
            b1.p[jp] = s1 * xh[dh][jp][1];
        }
        if (i & 1) {
            acc0b = __builtin_amdgcn_mfma_f32_16x16x32_f16(af.v, b0.v, acc0b, 0, 0, 0);
            acc1b = __builtin_amdgcn_mfma_f32_16x16x32_f16(af.v, b1.v, acc1b, 0, 0, 0);
        } else {
            acc0a = __builtin_amdgcn_mfma_f32_16x16x32_f16(af.v, b0.v, acc0a, 0, 0, 0);
            acc1a = __builtin_amdgcn_mfma_f32_16x16x32_f16(af.v, b1.v, acc1a, 0, 0, 0);
        }
    }
    const f32x4 acc0 = acc0a + acc0b;
    const f32x4 acc1 = acc1a + acc1b;
#pragma unroll
    for (int r = 0; r < 4; ++r) {
        accs[w][q*4 + r][gl]      = acc0[r];
        accs[w][q*4 + r][gl + 16] = acc1[r];
    }

    // ---- Ssum GEMM: waves 0,1 -> gene subtiles 0,1 ----
    if (w < 2) {
        Frag8 wf0, wf1;
        wf0.u = *(const uint4*)(cwA + ((NPAIR + 0) << 9) + lane * 8);
        wf1.u = *(const uint4*)(cwA + ((NPAIR + 1) << 9) + lane * 8);
        Frag8 x1f[2];
#pragma unroll
        for (int kk = 0; kk < 2; ++kk)
#pragma unroll
            for (int jp = 0; jp < 4; ++jp)
                x1f[kk].p[jp] = x1pT[gl + 16*w][kk*16 + q*4 + jp];
        f32x4 sa = {0.f,0.f,0.f,0.f};
        sa = __builtin_amdgcn_mfma_f32_16x16x32_f16(wf0.v, x1f[0].v, sa, 0, 0, 0);
        sa = __builtin_amdgcn_mfma_f32_16x16x32_f16(wf1.v, x1f[1].v, sa, 0, 0, 0);
#pragma unroll
        for (int r = 0; r < 4; ++r) ssum_s[q*4 + r][gl + 16*w] = sa[r];
    }
    __syncthreads();

    // ---- epilogue: thread -> (s = tid>>4, genes gx, gx+16) ----
    const int s  = tid >> 4;
    const int gx = tid & 15;
#pragma unroll
    for (int t = 0; t < 2; ++t) {
        const int gg = gx + 16 * t;
        const float vn = (accs[0][s][gg] + accs[1][s][gg])
                       + (accs[2][s][gg] + accs[3][s][gg]);
        const float ss   = ssum_s[s][gg];                 // = Ssum/4
        const float rvar = fmaxf(vn, 0.f) / (ss * ss);    // scale cancels
        out[s * G_GENES + gbase + gg] =
            __logf(ss) + 1.3862943611f - 0.5f * rvar;     // + log 4
        out[OUT_HALF + s * G_GENES + gbase + gg] = sqrtf(rvar);
    }
}

extern "C" void kernel_launch(void* const* d_in, const int* in_sizes, int n_in,
                              void* d_out, int out_size, void* d_ws, size_t ws_size,
                              hipStream_t stream) {
    const float* Z_mu      = (const float*)d_in[0];
    const float* Z_sigma   = (const float*)d_in[1];
    const float* corr      = (const float*)d_in[2];
    const float* cell_prob = (const float*)d_in[3];
    float* out = (float*)d_out;
    unsigned short* cwA = (unsigned short*)d_ws;   // 98 KB frag-ordered f16 A

    build_A<<<dim3(NPAIR + 2), dim3(64), 0, stream>>>(corr, cell_prob, cwA);

    const int gtiles = G_GENES / 32;               // 625, exact
    lognorm_main<<<dim3(gtiles), dim3(256), 0, stream>>>(
        Z_mu, Z_sigma, cwA, out);
}